// Round 5
// baseline (159.469 us; speedup 1.0000x reference)
//
#include <hip/hip_runtime.h>
#include <hip/hip_bf16.h>
#include <stdint.h>

// NT-Xent loss: B=4096, D=128, TEMP=0.5, N2=8192.
// loss = mean_i [ log sum_{j!=i} exp(2*sim_ij) - 2*pos_i ]
// sim computed by bf16 MFMA with A pre-scaled by 2*log2(e), so MFMA output
// IS the exp2 argument. Self-diagonal cancelled via rowsum init.
// R5: block-shared B staged in LDS via global_load_lds(16B), double-buffered,
// XOR-swizzled for bank-balanced ds_read_b128; raw v_exp_f32 epilogue;
// finalize merged into sim via completion counter.

#define BB 4096
#define N2 8192
#define DD 128
#define CSPLIT 32               // column splits
#define CW (N2 / CSPLIT)        // 256 cols per block
#define STAGE 64                // cols staged per LDS chunk
#define NCHUNK (CW / STAGE)     // 4 chunks per block
#define NBLOCKS (CSPLIT * (N2 / 256))   // 1024
#define TWO_LOG2E 2.8853900817779268f   // 2*log2(e)

using bf16 = __hip_bfloat16;
typedef __attribute__((ext_vector_type(8))) short short8;   // MFMA A/B frag
typedef __attribute__((ext_vector_type(4))) float float4v;  // MFMA C/D frag

__device__ inline void load_lds16(const void* g, void* l) {
  // LDS dest must be wave-uniform base + lane*16 [m104/m108]; caller ensures.
  __builtin_amdgcn_global_load_lds(
      (const __attribute__((address_space(1))) uint32_t*)g,
      (__attribute__((address_space(3))) uint32_t*)(uint32_t)(uintptr_t)l,
      16, 0, 0);
}

// ---------------- Kernel 1: normalize, bf16 casts, pos, rowsum/counter init
__global__ __launch_bounds__(256) void ntx_norm_kernel(
    const float* __restrict__ zi, const float* __restrict__ zj,
    bf16* __restrict__ zn, bf16* __restrict__ zn_s,
    float* __restrict__ rowsum, float* __restrict__ pos,
    int* __restrict__ counter) {
  const int wave = threadIdx.x >> 6;
  const int lane = threadIdx.x & 63;
  const int row = blockIdx.x * 4 + wave;   // 2048 blocks, 4 rows/block
  if (blockIdx.x == 0 && threadIdx.x == 0) counter[0] = 0;
  const float* own = (row < BB) ? (zi + (size_t)row * DD)
                                : (zj + (size_t)(row - BB) * DD);
  const float* par = (row < BB) ? (zj + (size_t)row * DD)
                                : (zi + (size_t)(row - BB) * DD);
  float2 v = ((const float2*)own)[lane];
  float2 w = ((const float2*)par)[lane];
  float s1 = v.x * v.x + v.y * v.y;   // |z|^2
  float s2 = w.x * w.x + w.y * w.y;   // |partner|^2
  float s3 = v.x * w.x + v.y * w.y;   // z . partner
  #pragma unroll
  for (int o = 32; o > 0; o >>= 1) {
    s1 += __shfl_xor(s1, o);
    s2 += __shfl_xor(s2, o);
    s3 += __shfl_xor(s3, o);
  }
  float nv = fmaxf(sqrtf(s1), 1e-8f);
  float nw = fmaxf(sqrtf(s2), 1e-8f);
  float rv = 1.0f / nv;
  bf16 bx = __float2bfloat16(v.x * rv);
  bf16 by = __float2bfloat16(v.y * rv);
  bf16 sx = __float2bfloat16(v.x * rv * TWO_LOG2E);   // A-side, pre-scaled
  bf16 sy = __float2bfloat16(v.y * rv * TWO_LOG2E);
  __hip_bfloat162 h2; h2.x = bx; h2.y = by;
  ((__hip_bfloat162*)(zn + (size_t)row * DD))[lane] = h2;
  __hip_bfloat162 g2; g2.x = sx; g2.y = sy;
  ((__hip_bfloat162*)(zn_s + (size_t)row * DD))[lane] = g2;
  // scaled self-dot in the SAME bf16-rounded precision the MFMA sees
  float sii = __bfloat162float(sx) * __bfloat162float(bx) +
              __bfloat162float(sy) * __bfloat162float(by);
  #pragma unroll
  for (int o = 32; o > 0; o >>= 1) sii += __shfl_xor(sii, o);
  if (lane == 0) {
    rowsum[row] = -__builtin_amdgcn_exp2f(sii);  // cancels diagonal of sim
    pos[row] = s3 / (nv * nw);                   // fp32 positive-pair cosine
  }
}

// ---------------- Kernel 2: fused sim + sum-exp + finalize -----------------
// grid (32, 32) = 1024 blocks. Block = 4 waves, 256 rows; block col range CW.
// B staged per 64-col chunk in LDS (global_load_lds, 2 buffers), XOR-swizzle:
// LDS slot (row lr, chunk i) holds global 16B-chunk (i ^ (lr&15)).
__global__ __launch_bounds__(256) void ntx_sim_kernel(
    const bf16* __restrict__ zn, const bf16* __restrict__ zn_s,
    float* __restrict__ rowsum, const float* __restrict__ pos,
    int* __restrict__ counter, float* __restrict__ out) {
  __shared__ short lds[2][STAGE * DD];   // 2 x 16 KB
  __shared__ int lastFlag;
  __shared__ float sm[4];
  const int tid  = threadIdx.x;
  const int wave = tid >> 6;
  const int lane = tid & 63;
  const int quad = lane >> 4;
  const int l15  = lane & 15;
  const short* zs  = (const short*)zn;
  const short* zss = (const short*)zn_s;

  const int rowBase  = blockIdx.y * 256 + wave * 64;
  const int colBase0 = blockIdx.x * CW;

  // A fragments (scaled copy): 4 row-tiles x 4 K-chunks = 64 VGPRs
  short8 a[4][4];
  #pragma unroll
  for (int t = 0; t < 4; t++) {
    const short* ap = zss + (size_t)(rowBase + t * 16 + l15) * DD + quad * 8;
    #pragma unroll
    for (int c = 0; c < 4; c++) a[t][c] = *(const short8*)(ap + c * 32);
  }

  float rs[4][4];
  #pragma unroll
  for (int t = 0; t < 4; t++)
    #pragma unroll
    for (int r = 0; r < 4; r++) rs[t][r] = 0.0f;

  // DMA: thread handles LDS slot (lr = j*16 + tid>>4, i = tid&15); source
  // chunk = i ^ (lr&15) = (tid&15) ^ (tid>>4), j-invariant.
  const int swz = (tid & 15) ^ (tid >> 4);

#define DMA(CHUNK, PB)                                                        \
  do {                                                                        \
    const char* gbase = (const char*)zs +                                     \
                        ((size_t)(colBase0 + (CHUNK) * STAGE) << 8);          \
    char* lbase = (char*)&lds[PB][0];                                         \
    _Pragma("unroll")                                                         \
    for (int j = 0; j < 4; j++) {                                             \
      const int lr = j * 16 + (tid >> 4);                                     \
      load_lds16(gbase + ((size_t)lr << 8) + (swz << 4),                      \
                 lbase + j * 4096 + tid * 16);                                \
    }                                                                         \
  } while (0)

  DMA(0, 0);
  __syncthreads();   // drains DMA (compiler emits vmcnt(0) before barrier)

  for (int c = 0; c < NCHUNK; c++) {
    if (c + 1 < NCHUNK) DMA(c + 1, (c + 1) & 1);
    const short* Bb = &lds[c & 1][0];
    #pragma unroll
    for (int ct = 0; ct < 4; ct++) {
      // B frags via swizzled ds_read_b128: slot = (kc*4+quad) ^ l15
      short8 b[4];
      #pragma unroll
      for (int kc = 0; kc < 4; kc++) {
        const int off = (ct * 16 + l15) * DD + (((kc * 4 + quad) ^ l15) << 3);
        b[kc] = *(const short8*)(Bb + off);
      }
      #pragma unroll
      for (int t = 0; t < 4; t++) {
        float4v acc = {0.f, 0.f, 0.f, 0.f};
        acc = __builtin_amdgcn_mfma_f32_16x16x32_bf16(a[t][0], b[0], acc, 0, 0, 0);
        acc = __builtin_amdgcn_mfma_f32_16x16x32_bf16(a[t][1], b[1], acc, 0, 0, 0);
        acc = __builtin_amdgcn_mfma_f32_16x16x32_bf16(a[t][2], b[2], acc, 0, 0, 0);
        acc = __builtin_amdgcn_mfma_f32_16x16x32_bf16(a[t][3], b[3], acc, 0, 0, 0);
        // C/D: col=l15, row=quad*4+r [m89/m91]; acc already = 2*log2e*sim
        #pragma unroll
        for (int r = 0; r < 4; r++)
          rs[t][r] += __builtin_amdgcn_exp2f(acc[r]);
      }
    }
    if (c + 1 < NCHUNK) __syncthreads();
  }
#undef DMA

  // reduce across the 16 lanes sharing each row, then one atomic each
  #pragma unroll
  for (int t = 0; t < 4; t++) {
    #pragma unroll
    for (int r = 0; r < 4; r++) {
      float s = rs[t][r];
      s += __shfl_xor(s, 1);
      s += __shfl_xor(s, 2);
      s += __shfl_xor(s, 4);
      s += __shfl_xor(s, 8);
      if (l15 == 0)
        atomicAdd(&rowsum[rowBase + t * 16 + quad * 4 + r], s);
    }
  }

  // ---- completion counter: last block finalizes ----
  __threadfence();            // release this block's rowsum atomics
  __syncthreads();
  if (tid == 0) {
    int old = atomicAdd(counter, 1);          // device-scope [m20]
    lastFlag = (old == NBLOCKS - 1);
  }
  __syncthreads();
  if (lastFlag) {
    __threadfence();          // acquire side
    float s = 0.f;
    for (int i = tid; i < N2; i += 256) {
      float r = __hip_atomic_load(&rowsum[i], __ATOMIC_RELAXED,
                                  __HIP_MEMORY_SCOPE_AGENT);
      s += __logf(r) - 2.0f * pos[i];
    }
    #pragma unroll
    for (int o = 32; o > 0; o >>= 1) s += __shfl_xor(s, o);
    if (lane == 0) sm[wave] = s;
    __syncthreads();
    if (tid == 0)
      out[0] = (sm[0] + sm[1] + sm[2] + sm[3]) / (float)N2;
  }
}

extern "C" void kernel_launch(void* const* d_in, const int* in_sizes, int n_in,
                              void* d_out, int out_size, void* d_ws, size_t ws_size,
                              hipStream_t stream) {
  const float* zi = (const float*)d_in[0];
  const float* zj = (const float*)d_in[1];
  float* out = (float*)d_out;

  char* ws = (char*)d_ws;
  bf16* zn   = (bf16*)ws;                                  // 2 MB
  bf16* zn_s = (bf16*)(ws + (size_t)N2 * DD * 2);          // 2 MB (A, scaled)
  float* rowsum = (float*)(ws + 2 * (size_t)N2 * DD * 2);  // 32 KB
  float* pos = rowsum + N2;                                // 32 KB
  int* counter = (int*)(pos + N2);                         // 4 B

  ntx_norm_kernel<<<N2 / 4, 256, 0, stream>>>(zi, zj, zn, zn_s, rowsum, pos,
                                              counter);
  dim3 grid(CSPLIT, N2 / 256);
  ntx_sim_kernel<<<grid, 256, 0, stream>>>(zn, zn_s, rowsum, pos, counter, out);
}

// Round 6
// 129.840 us; speedup vs baseline: 1.2282x; 1.2282x over previous
//
#include <hip/hip_runtime.h>
#include <hip/hip_bf16.h>
#include <stdint.h>

// NT-Xent loss: B=4096, D=128, TEMP=0.5, N2=8192.
// loss = mean_i [ log sum_{j!=i} exp(2*sim_ij) - 2*pos_i ]
// sim via bf16 MFMA; A-side pre-scaled by 2*log2(e) so MFMA output is the
// exp2 argument -> epilogue is raw v_exp_f32 + add. Diagonal cancelled via
// rowsum init. Finalize merged via completion counter.
//
// R6: back to R2's register-prefetch skeleton (best measured, 41.8 us).
//   + packed fragment layout: norm writes zn in MFMA fragment order, so
//     sim A/B loads are lane-contiguous 1KB dwordx4 (dense L2 streams).
//   + prefetch distance 2 (4 rotating B buffers, unroll-4).
//   + no LDS staging, no launch_bounds min-waves pin (R3/R5 lessons).

#define BB 4096
#define N2 8192
#define DD 128
#define CSPLIT 16               // column splits -> 512 blocks (R2's best)
#define CW (N2 / CSPLIT)        // 512 cols per block
#define NCT (CW / 16)           // 32 col-tiles per wave
#define NBLOCKS (CSPLIT * (N2 / 256))   // 512
#define TWO_LOG2E 2.8853900817779268f   // 2*log2(e)

// Packed layout (shorts): frag[tile][kc][slot(=lane)] of short8.
//   tile stride 2048, kc stride 512, slot stride 8.
//   slot lane: col15 = lane&15 (row index in tile), quad = lane>>4 (k-quad).
//   element (row, k): tile=row>>4, kc=k>>5, quad=(k&31)>>3, j=k&7
//     -> short index tile*2048 + kc*512 + (quad*16 + (row&15))*8 + j.

using bf16 = __hip_bfloat16;
typedef __attribute__((ext_vector_type(8))) short short8;   // MFMA A/B frag
typedef __attribute__((ext_vector_type(4))) float float4v;  // MFMA C/D frag

// ---------------- Kernel 1: normalize -> packed bf16 frags, pos, inits ----
__global__ __launch_bounds__(256) void ntx_norm_kernel(
    const float* __restrict__ zi, const float* __restrict__ zj,
    short* __restrict__ pB, short* __restrict__ pA,
    float* __restrict__ rowsum, float* __restrict__ pos,
    int* __restrict__ counter) {
  const int wave = threadIdx.x >> 6;
  const int lane = threadIdx.x & 63;
  const int row = blockIdx.x * 4 + wave;   // 2048 blocks, 4 rows/block
  if (blockIdx.x == 0 && threadIdx.x == 0) counter[0] = 0;
  const float* own = (row < BB) ? (zi + (size_t)row * DD)
                                : (zj + (size_t)(row - BB) * DD);
  const float* par = (row < BB) ? (zj + (size_t)row * DD)
                                : (zi + (size_t)(row - BB) * DD);
  float2 v = ((const float2*)own)[lane];   // elements 2*lane, 2*lane+1
  float2 w = ((const float2*)par)[lane];
  float s1 = v.x * v.x + v.y * v.y;   // |z|^2
  float s2 = w.x * w.x + w.y * w.y;   // |partner|^2
  float s3 = v.x * w.x + v.y * w.y;   // z . partner
  #pragma unroll
  for (int o = 32; o > 0; o >>= 1) {
    s1 += __shfl_xor(s1, o);
    s2 += __shfl_xor(s2, o);
    s3 += __shfl_xor(s3, o);
  }
  float nv = fmaxf(sqrtf(s1), 1e-8f);
  float nw = fmaxf(sqrtf(s2), 1e-8f);
  float rv = 1.0f / nv;
  bf16 bx = __float2bfloat16(v.x * rv);                // B-side (unscaled)
  bf16 by = __float2bfloat16(v.y * rv);
  bf16 sx = __float2bfloat16(v.x * rv * TWO_LOG2E);    // A-side (scaled)
  bf16 sy = __float2bfloat16(v.y * rv * TWO_LOG2E);
  // packed address for elements e=2*lane (j even) and e+1 (same short8 slot)
  const int tile = row >> 4, c15 = row & 15;
  const int kc = lane >> 4;
  const int quad = (lane & 15) >> 2;
  const int j = (2 * lane) & 7;
  const size_t off = (size_t)tile * 2048 + kc * 512 + (quad * 16 + c15) * 8 + j;
  __hip_bfloat162 h2; h2.x = bx; h2.y = by;
  *(__hip_bfloat162*)(pB + off) = h2;
  __hip_bfloat162 g2; g2.x = sx; g2.y = sy;
  *(__hip_bfloat162*)(pA + off) = g2;
  // scaled self-dot in the same bf16-rounded precision the MFMA sees
  float sii = __bfloat162float(sx) * __bfloat162float(bx) +
              __bfloat162float(sy) * __bfloat162float(by);
  #pragma unroll
  for (int o = 32; o > 0; o >>= 1) sii += __shfl_xor(sii, o);
  if (lane == 0) {
    rowsum[row] = -__builtin_amdgcn_exp2f(sii);  // cancels sim diagonal
    pos[row] = s3 / (nv * nw);                   // fp32 positive-pair cosine
  }
}

// ---------------- Kernel 2: fused sim + sum-exp + finalize -----------------
// grid (16, 32) = 512 blocks. Block = 4 waves; wave owns 64 rows, iterates
// 32 col-tiles. B prefetched 2 tiles ahead through 4 rotating reg buffers.
__global__ __launch_bounds__(256) void ntx_sim_kernel(
    const short* __restrict__ pB, const short* __restrict__ pA,
    float* __restrict__ rowsum, const float* __restrict__ pos,
    int* __restrict__ counter, float* __restrict__ out) {
  __shared__ float sm[4];
  __shared__ int lastFlag;
  const int tid  = threadIdx.x;
  const int wave = tid >> 6;
  const int lane = tid & 63;
  const int quad = lane >> 4;
  const int l15  = lane & 15;

  const int rowBase   = blockIdx.y * 256 + wave * 64;
  const int rowTile0  = rowBase >> 4;              // 4 consecutive tiles
  const int colTile0  = blockIdx.x * NCT;

  // A fragments (scaled): 4 row-tiles x 4 kc, lane-contiguous 1KB loads
  short8 a[4][4];
  #pragma unroll
  for (int t = 0; t < 4; t++) {
    const short* ap = pA + (size_t)(rowTile0 + t) * 2048 + lane * 8;
    #pragma unroll
    for (int c = 0; c < 4; c++) a[t][c] = *(const short8*)(ap + c * 512);
  }

  float rs[4][4];
  #pragma unroll
  for (int t = 0; t < 4; t++)
    #pragma unroll
    for (int r = 0; r < 4; r++) rs[t][r] = 0.0f;

  const short* bb = pB + (size_t)colTile0 * 2048 + lane * 8;

#define LOADB(BUF, CT)                                                        \
  do {                                                                        \
    const short* p_ = bb + (size_t)(CT) * 2048;                               \
    BUF[0] = *(const short8*)(p_);                                            \
    BUF[1] = *(const short8*)(p_ + 512);                                      \
    BUF[2] = *(const short8*)(p_ + 1024);                                     \
    BUF[3] = *(const short8*)(p_ + 1536);                                     \
  } while (0)

#define COMPUTE(BUF)                                                          \
  do {                                                                        \
    _Pragma("unroll")                                                         \
    for (int t = 0; t < 4; t++) {                                             \
      float4v acc = {0.f, 0.f, 0.f, 0.f};                                     \
      acc = __builtin_amdgcn_mfma_f32_16x16x32_bf16(a[t][0], BUF[0], acc, 0, 0, 0); \
      acc = __builtin_amdgcn_mfma_f32_16x16x32_bf16(a[t][1], BUF[1], acc, 0, 0, 0); \
      acc = __builtin_amdgcn_mfma_f32_16x16x32_bf16(a[t][2], BUF[2], acc, 0, 0, 0); \
      acc = __builtin_amdgcn_mfma_f32_16x16x32_bf16(a[t][3], BUF[3], acc, 0, 0, 0); \
      _Pragma("unroll")                                                       \
      for (int r = 0; r < 4; r++)                                             \
        rs[t][r] += __builtin_amdgcn_exp2f(acc[r]);                           \
    }                                                                         \
  } while (0)

  short8 b0[4], b1[4], b2[4], b3[4];
  LOADB(b0, 0);
  LOADB(b1, 1);
  for (int c = 0; c < NCT; c += 4) {
    LOADB(b2, (c + 2) & (NCT - 1));   // wrap: tail reloads tile 0/1, harmless
    COMPUTE(b0);
    LOADB(b3, (c + 3) & (NCT - 1));
    COMPUTE(b1);
    LOADB(b0, (c + 4) & (NCT - 1));
    COMPUTE(b2);
    LOADB(b1, (c + 5) & (NCT - 1));
    COMPUTE(b3);
  }
#undef LOADB
#undef COMPUTE

  // reduce across the 16 lanes sharing each row (C/D: col=l15, row=quad*4+r)
  #pragma unroll
  for (int t = 0; t < 4; t++) {
    #pragma unroll
    for (int r = 0; r < 4; r++) {
      float s = rs[t][r];
      s += __shfl_xor(s, 1);
      s += __shfl_xor(s, 2);
      s += __shfl_xor(s, 4);
      s += __shfl_xor(s, 8);
      if (l15 == 0)
        atomicAdd(&rowsum[rowBase + t * 16 + quad * 4 + r], s);
    }
  }

  // ---- completion counter: last block finalizes ----
  __threadfence();
  __syncthreads();
  if (tid == 0) {
    int old = atomicAdd(counter, 1);
    lastFlag = (old == NBLOCKS - 1);
  }
  __syncthreads();
  if (lastFlag) {
    __threadfence();
    float s = 0.f;
    for (int i = tid; i < N2; i += 256) {
      float r = __hip_atomic_load(&rowsum[i], __ATOMIC_RELAXED,
                                  __HIP_MEMORY_SCOPE_AGENT);
      s += __logf(r) - 2.0f * pos[i];
    }
    #pragma unroll
    for (int o = 32; o > 0; o >>= 1) s += __shfl_xor(s, o);
    if (lane == 0) sm[wave] = s;
    __syncthreads();
    if (tid == 0)
      out[0] = (sm[0] + sm[1] + sm[2] + sm[3]) / (float)N2;
  }
}

extern "C" void kernel_launch(void* const* d_in, const int* in_sizes, int n_in,
                              void* d_out, int out_size, void* d_ws, size_t ws_size,
                              hipStream_t stream) {
  const float* zi = (const float*)d_in[0];
  const float* zj = (const float*)d_in[1];
  float* out = (float*)d_out;

  char* ws = (char*)d_ws;
  short* pB = (short*)ws;                                  // 2 MB packed B
  short* pA = (short*)(ws + (size_t)N2 * DD * 2);          // 2 MB packed A
  float* rowsum = (float*)(ws + 2 * (size_t)N2 * DD * 2);  // 32 KB
  float* pos = rowsum + N2;                                // 32 KB
  int* counter = (int*)(pos + N2);                         // 4 B

  ntx_norm_kernel<<<N2 / 4, 256, 0, stream>>>(zi, zj, pB, pA, rowsum, pos,
                                              counter);
  dim3 grid(CSPLIT, N2 / 256);
  ntx_sim_kernel<<<grid, 256, 0, stream>>>(pB, pA, rowsum, pos, counter, out);
}

// Round 7
// 101.651 us; speedup vs baseline: 1.5688x; 1.2773x over previous
//
#include <hip/hip_runtime.h>
#include <hip/hip_bf16.h>
#include <stdint.h>

// NT-Xent loss: B=4096, D=128, TEMP=0.5, N2=8192.
// loss = mean_i [ log sum_{j!=i} exp(2*sim_ij) - 2*pos_i ]
// sim via bf16 MFMA; A-side pre-scaled by 2*log2(e) so MFMA output is the
// exp2 argument -> epilogue is raw v_exp_f32 + add. Diagonal cancelled via
// rowsum init = -exp2(scaled self-dot in bf16 precision).
//
// R7: one-shot LDS staging. Register-prefetch variants (R2/R4/R6 =
// 41.8/49/76.5 us) are all ~85% stalled on loaded-L2 latency at 2 waves/SIMD.
// Here each block stages its whole 128-col B range (32 KB) into LDS via
// global_load_lds once (ONE barrier), then the col-loop is pure
// LDS->MFMA->exp2. XOR-swizzled placement (verified in R5) keeps the DMA's
// lane-contiguity constraint and makes ds_read_b128 bank-balanced.
// R5's failure causes removed: no per-chunk double-buffer barriers, no merged
// finalize tail, lean live set (target VGPR <= 128, no launch_bounds pin).

#define BB 4096
#define N2 8192
#define DD 128
#define CSPLIT 64               // column splits
#define CW (N2 / CSPLIT)        // 128 cols per block
#define NCT (CW / 16)           // 8 col-tiles per block
#define TWO_LOG2E 2.8853900817779268f   // 2*log2(e)

using bf16 = __hip_bfloat16;
typedef __attribute__((ext_vector_type(8))) short short8;   // MFMA A/B frag
typedef __attribute__((ext_vector_type(4))) float float4v;  // MFMA C/D frag

__device__ inline void load_lds16(const void* g, void* l) {
  // LDS dest must be wave-uniform base + lane*16 [m104/m108]; caller ensures.
  __builtin_amdgcn_global_load_lds(
      (const __attribute__((address_space(1))) uint32_t*)g,
      (__attribute__((address_space(3))) uint32_t*)(uint32_t)(uintptr_t)l,
      16, 0, 0);
}

// ---------------- Kernel 1: normalize, bf16 casts, pos, rowsum init -------
__global__ __launch_bounds__(256) void ntx_norm_kernel(
    const float* __restrict__ zi, const float* __restrict__ zj,
    bf16* __restrict__ zn, bf16* __restrict__ zn_s,
    float* __restrict__ rowsum, float* __restrict__ pos) {
  const int wave = threadIdx.x >> 6;
  const int lane = threadIdx.x & 63;
  const int row = blockIdx.x * 4 + wave;   // 2048 blocks, 4 rows/block
  const float* own = (row < BB) ? (zi + (size_t)row * DD)
                                : (zj + (size_t)(row - BB) * DD);
  const float* par = (row < BB) ? (zj + (size_t)row * DD)
                                : (zi + (size_t)(row - BB) * DD);
  float2 v = ((const float2*)own)[lane];
  float2 w = ((const float2*)par)[lane];
  float s1 = v.x * v.x + v.y * v.y;   // |z|^2
  float s2 = w.x * w.x + w.y * w.y;   // |partner|^2
  float s3 = v.x * w.x + v.y * w.y;   // z . partner
  #pragma unroll
  for (int o = 32; o > 0; o >>= 1) {
    s1 += __shfl_xor(s1, o);
    s2 += __shfl_xor(s2, o);
    s3 += __shfl_xor(s3, o);
  }
  float nv = fmaxf(sqrtf(s1), 1e-8f);
  float nw = fmaxf(sqrtf(s2), 1e-8f);
  float rv = 1.0f / nv;
  bf16 bx = __float2bfloat16(v.x * rv);                // B-side (unscaled)
  bf16 by = __float2bfloat16(v.y * rv);
  bf16 sx = __float2bfloat16(v.x * rv * TWO_LOG2E);    // A-side (scaled)
  bf16 sy = __float2bfloat16(v.y * rv * TWO_LOG2E);
  __hip_bfloat162 h2; h2.x = bx; h2.y = by;
  ((__hip_bfloat162*)(zn + (size_t)row * DD))[lane] = h2;
  __hip_bfloat162 g2; g2.x = sx; g2.y = sy;
  ((__hip_bfloat162*)(zn_s + (size_t)row * DD))[lane] = g2;
  // scaled self-dot in the same bf16-rounded precision the MFMA sees
  float sii = __bfloat162float(sx) * __bfloat162float(bx) +
              __bfloat162float(sy) * __bfloat162float(by);
  #pragma unroll
  for (int o = 32; o > 0; o >>= 1) sii += __shfl_xor(sii, o);
  if (lane == 0) {
    rowsum[row] = -__builtin_amdgcn_exp2f(sii);  // cancels sim diagonal
    pos[row] = s3 / (nv * nw);                   // fp32 positive-pair cosine
  }
}

// ---------------- Kernel 2: fused sim + sum-exp ----------------------------
// grid (64, 32) = 2048 blocks. Block = 4 waves, 256 rows, 128-col range.
// Stage B[colBase0 .. +128) (32 KB) into LDS once; loop 8 col-tiles from LDS.
// LDS layout: row lr (256 B) holds its 16 16B-chunks XOR-swizzled:
// chunk q stored at slot q ^ (lr & 15)  [R5-verified].
__global__ __launch_bounds__(256) void ntx_sim_kernel(
    const short* __restrict__ zn, const short* __restrict__ zn_s,
    float* __restrict__ rowsum) {
  __shared__ short lds[CW * DD];   // 32 KB
  const int tid  = threadIdx.x;
  const int wave = tid >> 6;
  const int lane = tid & 63;
  const int quad = lane >> 4;
  const int l15  = lane & 15;

  const int rowBase  = blockIdx.y * 256 + wave * 64;
  const int colBase0 = blockIdx.x * CW;

  // ---- DMA: stage all 128 B-rows. Thread t, iter j handles LDS row
  // lr = j*16 + (t>>4), slot s = t&15; source chunk = s ^ (lr&15)
  // = (t&15) ^ (t>>4), j-invariant. Dest = wave-uniform + lane*16. ----
  {
    const int swz = (tid & 15) ^ (tid >> 4);
    const char* gbase = (const char*)zn + ((size_t)colBase0 << 8);
    char* lbase = (char*)lds;
    #pragma unroll
    for (int j = 0; j < 8; j++) {
      const int lr = j * 16 + (tid >> 4);
      load_lds16(gbase + ((size_t)lr << 8) + (swz << 4),
                 lbase + j * 4096 + tid * 16);
    }
  }

  // A fragments (scaled): 4 row-tiles x 4 kc = 64 VGPRs (overlaps DMA wait)
  short8 a[4][4];
  #pragma unroll
  for (int t = 0; t < 4; t++) {
    const short* ap = zn_s + (size_t)(rowBase + t * 16 + l15) * DD + quad * 8;
    #pragma unroll
    for (int c = 0; c < 4; c++) a[t][c] = *(const short8*)(ap + c * 32);
  }

  float rs[4][4];
  #pragma unroll
  for (int t = 0; t < 4; t++)
    #pragma unroll
    for (int r = 0; r < 4; r++) rs[t][r] = 0.0f;

  __syncthreads();   // drains DMA (compiler emits vmcnt(0) before barrier)

  #pragma unroll 2
  for (int ct = 0; ct < NCT; ct++) {
    // B frags via swizzled ds_read_b128: slot = (kc*4+quad) ^ l15
    short8 b[4];
    #pragma unroll
    for (int kc = 0; kc < 4; kc++) {
      const int off = (ct * 16 + l15) * DD + (((kc * 4 + quad) ^ l15) << 3);
      b[kc] = *(const short8*)(lds + off);
    }
    #pragma unroll
    for (int t = 0; t < 4; t++) {
      float4v acc = {0.f, 0.f, 0.f, 0.f};
      acc = __builtin_amdgcn_mfma_f32_16x16x32_bf16(a[t][0], b[0], acc, 0, 0, 0);
      acc = __builtin_amdgcn_mfma_f32_16x16x32_bf16(a[t][1], b[1], acc, 0, 0, 0);
      acc = __builtin_amdgcn_mfma_f32_16x16x32_bf16(a[t][2], b[2], acc, 0, 0, 0);
      acc = __builtin_amdgcn_mfma_f32_16x16x32_bf16(a[t][3], b[3], acc, 0, 0, 0);
      // C/D: col=l15, row=quad*4+r [m89/m91]; acc already = 2*log2e*sim
      #pragma unroll
      for (int r = 0; r < 4; r++)
        rs[t][r] += __builtin_amdgcn_exp2f(acc[r]);
    }
  }

  // reduce across the 16 lanes sharing each row, then one atomic each
  #pragma unroll
  for (int t = 0; t < 4; t++) {
    #pragma unroll
    for (int r = 0; r < 4; r++) {
      float s = rs[t][r];
      s += __shfl_xor(s, 1);
      s += __shfl_xor(s, 2);
      s += __shfl_xor(s, 4);
      s += __shfl_xor(s, 8);
      if (l15 == 0)
        atomicAdd(&rowsum[rowBase + t * 16 + quad * 4 + r], s);
    }
  }
}

// ---------------- Kernel 3: finalize --------------------------------------
__global__ __launch_bounds__(1024) void ntx_finalize_kernel(
    const float* __restrict__ rowsum, const float* __restrict__ pos,
    float* __restrict__ out) {
  float s = 0.f;
  for (int i = threadIdx.x; i < N2; i += 1024)
    s += __logf(rowsum[i]) - 2.0f * pos[i];
  #pragma unroll
  for (int o = 32; o > 0; o >>= 1) s += __shfl_xor(s, o);
  __shared__ float sm[16];
  const int wave = threadIdx.x >> 6;
  const int lane = threadIdx.x & 63;
  if (lane == 0) sm[wave] = s;
  __syncthreads();
  if (threadIdx.x == 0) {
    float t = 0.f;
    #pragma unroll
    for (int i = 0; i < 16; i++) t += sm[i];
    out[0] = t / (float)N2;
  }
}

extern "C" void kernel_launch(void* const* d_in, const int* in_sizes, int n_in,
                              void* d_out, int out_size, void* d_ws, size_t ws_size,
                              hipStream_t stream) {
  const float* zi = (const float*)d_in[0];
  const float* zj = (const float*)d_in[1];
  float* out = (float*)d_out;

  char* ws = (char*)d_ws;
  bf16* zn   = (bf16*)ws;                                  // 2 MB (B-side)
  bf16* zn_s = (bf16*)(ws + (size_t)N2 * DD * 2);          // 2 MB (A, scaled)
  float* rowsum = (float*)(ws + 2 * (size_t)N2 * DD * 2);  // 32 KB
  float* pos = rowsum + N2;                                // 32 KB

  ntx_norm_kernel<<<N2 / 4, 256, 0, stream>>>(zi, zj, zn, zn_s, rowsum, pos);
  dim3 grid(CSPLIT, N2 / 256);
  ntx_sim_kernel<<<grid, 256, 0, stream>>>((const short*)zn, (const short*)zn_s,
                                           rowsum);
  ntx_finalize_kernel<<<1, 1024, 0, stream>>>(rowsum, pos, out);
}